// Round 11
// baseline (347.891 us; speedup 1.0000x reference)
//
#include <hip/hip_runtime.h>
#include <stdint.h>

// Problem constants
#define NDM   1024   // D_MODEL
#define NDS   16     // D_STATE
#define NDC   4      // D_CONV
#define NDI   2048   // D_INNER
#define NB    2      // BATCH
#define NL    2048   // SEQ
#define MROWS (NB*NL)   // 4096
#define CCH   32     // scan chunks  (scratch = NB*NDI*CCH*NDS*4 = 8.39MB each)
#define CLEN  64     // NL / CCH

typedef __bf16 bf16x8 __attribute__((ext_vector_type(8)));
typedef float  f32x4  __attribute__((ext_vector_type(4)));
typedef short  short8 __attribute__((ext_vector_type(8)));

__device__ __forceinline__ short f2bf(float f) {
  union { float f; unsigned u; } x; x.f = f;
  unsigned r = (x.u + 0x7FFFu + ((x.u >> 16) & 1u)) >> 16;
  return (short)r;
}

// Fragment-order Global layout (FG) for a logical row-major (R x K) bf16
// matrix: 16-row groups; chunk (k8, r) of 8 shorts at k8*128 + (r&15)*8.
// A 16x32 MFMA fragment is a CONTIGUOUS 1KB block in lane order.
__device__ __forceinline__ size_t fgoff(int row, int k8, int K) {
  return (size_t)(row >> 4) * K * 16 + (size_t)k8 * 128 + (row & 15) * 8;
}

// ---------------------------------------------------------------------------
// x (f32, MROWS x 1024 row-major) -> FG bf16 via LDS slab (coalesced both ways)
__global__ __launch_bounds__(256) void cvt_fg_kernel(
    const float* __restrict__ in, short* __restrict__ out) {
  __shared__ short slab[16][1032];         // stride 2064B = 16B-aligned
  const int tid = threadIdx.x;
  const int g = blockIdx.x;                // 16-row group
  const float* p = in + (size_t)g * 16 * 1024;
  #pragma unroll
  for (int u = 0; u < 8; ++u) {
    int unit = u * 256 + tid;              // 2048 = 16 rows x 128 chunks
    int rr = unit >> 7, cc = unit & 127;
    const float* rp = p + (size_t)rr * 1024 + cc * 8;
    #pragma unroll
    for (int e = 0; e < 8; ++e) slab[rr][cc * 8 + e] = f2bf(rp[e]);
  }
  __syncthreads();
  short* op = out + (size_t)g * 16384;     // whole group contiguous in FG
  #pragma unroll
  for (int u = 0; u < 8; ++u) {
    int u2 = u * 256 + tid;
    int rr = u2 & 15, k8 = u2 >> 4;        // rr-minor -> contiguous 16B chunks
    *(short8*)&op[k8 * 128 + rr * 8] = *(short8*)&slab[rr][k8 * 8];
  }
}

// ---------------------------------------------------------------------------
// W (K x N f32) -> FG bf16 of W^T (N rows, K cols). 32n x 64k tiles.
__global__ __launch_bounds__(256) void transpose_fg_kernel(
    const float* __restrict__ in, short* __restrict__ out, int K, int N) {
  __shared__ float t[64][33];
  const int tx = threadIdx.x, ty = threadIdx.y;   // 32, 8
  const int n0 = blockIdx.x * 32, k0 = blockIdx.y * 64;
  #pragma unroll
  for (int i = 0; i < 64; i += 8)
    t[ty + i][tx] = in[(size_t)(k0 + ty + i) * N + n0 + tx];
  __syncthreads();
  const int n = n0 + tx, k8 = (k0 >> 3) + ty;
  short8 v;
  #pragma unroll
  for (int e = 0; e < 8; ++e) v[e] = f2bf(t[ty * 8 + e][tx]);
  *(short8*)&out[fgoff(n, k8, K)] = v;
}

// ---------------------------------------------------------------------------
// Register-direct FG bf16 TN GEMM: C = A_fg(MxK) * B_fg(NxK)^T + bias.
// NO LDS, NO barriers: each wave loads its own MFMA fragments straight from
// the FG layout (each load = contiguous 1KB, fully coalesced) into VGPRs,
// 2-stage register double-buffer; compiler pipelines with counted vmcnt
// (AITER buffer_load<->MFMA pattern). Fragment sharing lost (2 waves/frag)
// is absorbed by L2. XCD-aware block swizzle for L2 locality.
// BN in {64,128}; EPI: 0 = bias only, 1 = softplus(v + bias).
template<int BN, int EPI>
__global__ __launch_bounds__(256, 2) void gemm_fg_kernel(
    const short* __restrict__ A, const short* __restrict__ Bt,
    const float* __restrict__ bias, float* __restrict__ C,
    int M, int N, int K)
{
  const int tid  = threadIdx.x;
  const int lane = tid & 63;
  const int w    = tid >> 6;      // wave 0..3
  const int wM   = w >> 1;
  const int wN   = w & 1;
  const int g    = lane >> 4;
  const int r    = lane & 15;

  constexpr int FN = BN / 32;     // N fragments per wave (4 or 2)

  // XCD-aware swizzle (bijective: nwg % 8 == 0 for all our grids)
  const int nx  = gridDim.x;
  const int nwg = nx * gridDim.y;
  const int bid = blockIdx.y * nx + blockIdx.x;
  const int swz = (bid & 7) * (nwg >> 3) + (bid >> 3);
  const int bm  = (swz / nx) * 128;
  const int bn  = (swz % nx) * BN;

  const short* pA[4];
  const short* pB[FN];
  #pragma unroll
  for (int m = 0; m < 4; ++m)
    pA[m] = A + (size_t)((bm >> 4) + wM * 4 + m) * K * 16 + lane * 8;
  #pragma unroll
  for (int n = 0; n < FN; ++n)
    pB[n] = Bt + (size_t)((bn >> 4) + wN * FN + n) * K * 16 + lane * 8;

  f32x4 acc[4][FN];
  #pragma unroll
  for (int m = 0; m < 4; ++m)
    #pragma unroll
    for (int n = 0; n < FN; ++n)
      acc[m][n] = (f32x4){0.f, 0.f, 0.f, 0.f};

  // 2-stage register double-buffer over BK=32 slices (K offset kb -> +kb*16)
  bf16x8 a0[4], b0[FN], a1[4], b1[FN];
  #pragma unroll
  for (int m = 0; m < 4; ++m) a0[m] = *(const bf16x8*)(pA[m]);
  #pragma unroll
  for (int n = 0; n < FN; ++n) b0[n] = *(const bf16x8*)(pB[n]);

  for (int kb = 0; kb < K; kb += 64) {
    if (kb + 32 < K) {
      #pragma unroll
      for (int m = 0; m < 4; ++m)
        a1[m] = *(const bf16x8*)(pA[m] + (size_t)(kb + 32) * 16);
      #pragma unroll
      for (int n = 0; n < FN; ++n)
        b1[n] = *(const bf16x8*)(pB[n] + (size_t)(kb + 32) * 16);
    }
    #pragma unroll
    for (int m = 0; m < 4; ++m)
      #pragma unroll
      for (int n = 0; n < FN; ++n)
        acc[m][n] = __builtin_amdgcn_mfma_f32_16x16x32_bf16(
            a0[m], b0[n], acc[m][n], 0, 0, 0);

    if (kb + 64 < K) {
      #pragma unroll
      for (int m = 0; m < 4; ++m)
        a0[m] = *(const bf16x8*)(pA[m] + (size_t)(kb + 64) * 16);
      #pragma unroll
      for (int n = 0; n < FN; ++n)
        b0[n] = *(const bf16x8*)(pB[n] + (size_t)(kb + 64) * 16);
    }
    #pragma unroll
    for (int m = 0; m < 4; ++m)
      #pragma unroll
      for (int n = 0; n < FN; ++n)
        acc[m][n] = __builtin_amdgcn_mfma_f32_16x16x32_bf16(
            a1[m], b1[n], acc[m][n], 0, 0, 0);
  }

  // D layout (verified m89/m91): col = lane&15, row = (lane>>4)*4 + e
  #pragma unroll
  for (int m = 0; m < 4; ++m) {
    const int row0 = bm + wM * 64 + m * 16 + g * 4;
    #pragma unroll
    for (int n = 0; n < FN; ++n) {
      const int col = bn + wN * (BN / 2) + n * 16 + r;
      const float bv = bias[col];
      #pragma unroll
      for (int e = 0; e < 4; ++e) {
        float v = acc[m][n][e] + bv;
        if (EPI == 1) v = (v > 15.f) ? v : log1pf(__expf(v));
        C[(size_t)(row0 + e) * N + col] = v;
      }
    }
  }
}

// ---------------------------------------------------------------------------
// depthwise causal conv (width 4) + bias + SiLU, slab version.
__global__ __launch_bounds__(256) void conv_silu_kernel(
    const float* __restrict__ xz, const float* __restrict__ cw,
    const float* __restrict__ cb, float* __restrict__ xh,
    short* __restrict__ xhbf) {
  __shared__ short slab[16][528];          // stride 1056B = 16B-aligned
  const int tid = threadIdx.x;
  const int c0 = blockIdx.x * 512;
  const int r0 = blockIdx.y * 16;
  const int b  = r0 >> 11;
  const int t0 = r0 & (NL - 1);
  const float* zbase = xz + ((size_t)b * NL) * (2 * NDI);

  #pragma unroll
  for (int u = 0; u < 4; ++u) {
    int unit = u * 256 + tid;              // 1024 = 16 rows x 64 chunks
    int rr = unit >> 6, cc = unit & 63;
    int t = t0 + rr, c = c0 + cc * 8;
    float acc[8];
    #pragma unroll
    for (int e = 0; e < 8; ++e) acc[e] = cb[c + e];
    #pragma unroll
    for (int k = 0; k < NDC; ++k) {
      int tt = t - (NDC - 1) + k;
      if (tt >= 0) {
        const float* rp = zbase + (size_t)tt * (2 * NDI) + c;
        #pragma unroll
        for (int e = 0; e < 8; ++e) acc[e] += cw[(c + e) * NDC + k] * rp[e];
      }
    }
    float* xo = xh + (size_t)(r0 + rr) * NDI + c;
    #pragma unroll
    for (int e = 0; e < 8; ++e) {
      float s = acc[e] / (1.f + __expf(-acc[e]));
      xo[e] = s;
      slab[rr][cc * 8 + e] = f2bf(s);
    }
  }
  __syncthreads();
  short* op = xhbf + (size_t)(r0 >> 4) * NDI * 16 + (size_t)(c0 >> 3) * 128;
  #pragma unroll
  for (int u = 0; u < 4; ++u) {
    int u2 = u * 256 + tid;
    int rr = u2 & 15, q = u2 >> 4;         // rr-minor -> contiguous
    *(short8*)&op[q * 128 + rr * 8] = *(short8*)&slab[rr][q * 8];
  }
}

// ---------------------------------------------------------------------------
// Bmat[row, s] = sum_c xh[row,c] * W_x[c, 16+s] + b_x[16+s]; one wave per row
__global__ __launch_bounds__(256) void bmat_kernel(
    const float* __restrict__ xh, const float* __restrict__ Wx,
    const float* __restrict__ bx, float* __restrict__ Bm) {
  const int row  = blockIdx.x * 4 + (threadIdx.x >> 6);
  const int lane = threadIdx.x & 63;
  const int s = lane & 15, q = lane >> 4;
  const float* xr = xh + (size_t)row * NDI;
  float acc = 0.f;
  for (int c = q * 512; c < (q + 1) * 512; ++c)
    acc += xr[c] * Wx[c * (2 * NDS) + NDS + s];
  acc += __shfl_xor(acc, 16);
  acc += __shfl_xor(acc, 32);
  if (lane < 16) Bm[(size_t)row * NDS + s] = acc + bx[NDS + s];
}

// ---------------------------------------------------------------------------
// scan scratch layout: [b][k][c][s] -> offset ((b*CCH+k)*NDI+c)*NDS+s
__device__ __forceinline__ size_t scoff(int b, int k, int c) {
  return (((size_t)b * CCH + k) * NDI + c) * NDS;
}

// phase 1: thread = (b, c, chunk); 16 states in registers.
__global__ __launch_bounds__(256) void scan_p1_kernel(
    const float* __restrict__ delta, const float* __restrict__ Bm,
    const float* __restrict__ xh, const float* __restrict__ A_log,
    float* __restrict__ Pbuf, float* __restrict__ Hend) {
  const int i = blockIdx.x * 256 + threadIdx.x;     // NB*CCH*NDI
  const int c = i & (NDI - 1);
  const int k = (i >> 11) & (CCH - 1);
  const int b = i >> 16;
  const int t0 = k * CLEN;

  float Av[NDS];
  #pragma unroll
  for (int s = 0; s < NDS; ++s) Av[s] = -__expf(A_log[c * NDS + s]);

  const float* dp = delta + ((size_t)(b * NL + t0)) * NDI + c;
  const float* up = xh    + ((size_t)(b * NL + t0)) * NDI + c;
  const f32x4* Bp = (const f32x4*)(Bm + ((size_t)(b * NL + t0)) * NDS);

  float h[NDS], P[NDS];
  #pragma unroll
  for (int s = 0; s < NDS; ++s) { h[s] = 0.f; P[s] = 1.f; }

  #pragma unroll 4
  for (int j = 0; j < CLEN; ++j) {
    const float d = dp[(size_t)j * NDI];
    const float u = up[(size_t)j * NDI];
    f32x4 B0 = Bp[j * 4 + 0], B1 = Bp[j * 4 + 1];
    f32x4 B2 = Bp[j * 4 + 2], B3 = Bp[j * 4 + 3];
    const float du = d * u;
    float Bv[NDS];
    #pragma unroll
    for (int e = 0; e < 4; ++e) {
      Bv[e] = B0[e]; Bv[4 + e] = B1[e]; Bv[8 + e] = B2[e]; Bv[12 + e] = B3[e];
    }
    #pragma unroll
    for (int s = 0; s < NDS; ++s) {
      float dA = __expf(d * Av[s]);
      h[s] = dA * h[s] + du * Bv[s];
      P[s] *= dA;
    }
  }

  const size_t base = scoff(b, k, c);
  #pragma unroll
  for (int q = 0; q < 4; ++q) {
    *(f32x4*)&Pbuf[base + q * 4] = (f32x4){P[q*4], P[q*4+1], P[q*4+2], P[q*4+3]};
    *(f32x4*)&Hend[base + q * 4] = (f32x4){h[q*4], h[q*4+1], h[q*4+2], h[q*4+3]};
  }
}

// ---------------------------------------------------------------------------
// phase 2: thread = (b, c, s); serial combine across the chunks.
__global__ __launch_bounds__(256) void scan_p2_kernel(
    const float* __restrict__ Pbuf, const float* __restrict__ Hend,
    float* __restrict__ Hin) {
  const int i = blockIdx.x * 256 + threadIdx.x;     // 65536
  const int s = i & (NDS - 1);
  const int c = (i >> 4) & (NDI - 1);
  const int b = i >> 15;
  const size_t step = (size_t)NDI * NDS;
  const size_t base = scoff(b, 0, c) + s;
  float h = 0.f;
  #pragma unroll 8
  for (int k = 0; k < CCH; ++k) {
    Hin[base + (size_t)k * step] = h;
    h = Hend[base + (size_t)k * step] + Pbuf[base + (size_t)k * step] * h;
  }
}

// ---------------------------------------------------------------------------
// phase 3 + merge: rescan from h_in; y = (sum_s h + u*D) * silu(z);
// LDS slab-transpose -> FG bf16 output, rr-minor drain (coalesced).
__global__ __launch_bounds__(256) void scan_p3_kernel(
    const float* __restrict__ delta, const float* __restrict__ Bm,
    const float* __restrict__ xh, const float* __restrict__ A_log,
    const float* __restrict__ Hin, const float* __restrict__ Dvec,
    const float* __restrict__ xz, short* __restrict__ ybf) {
  const int tid = threadIdx.x;
  const int i = blockIdx.x * 256 + tid;
  const int c = i & (NDI - 1);
  const int k = (i >> 11) & (CCH - 1);
  const int b = i >> 16;
  const int t0 = k * CLEN;
  const int cb0 = (blockIdx.x * 256) & (NDI - 1);   // block's base channel

  __shared__ float ylds[16][257];

  float Av[NDS];
  #pragma unroll
  for (int s = 0; s < NDS; ++s) Av[s] = -__expf(A_log[c * NDS + s]);
  const float dcoef = Dvec[c];

  const float* dp = delta + ((size_t)(b * NL + t0)) * NDI + c;
  const float* up = xh    + ((size_t)(b * NL + t0)) * NDI + c;
  const f32x4* Bp = (const f32x4*)(Bm + ((size_t)(b * NL + t0)) * NDS);
  const float* zp = xz    + ((size_t)(b * NL + t0)) * (2 * NDI) + NDI + c;

  const size_t base = scoff(b, k, c);
  float h[NDS];
  #pragma unroll
  for (int s = 0; s < NDS; ++s) h[s] = Hin[base + s];

  for (int j = 0; j < CLEN; ++j) {
    const float d = dp[(size_t)j * NDI];
    const float u = up[(size_t)j * NDI];
    f32x4 B0 = Bp[j * 4 + 0], B1 = Bp[j * 4 + 1];
    f32x4 B2 = Bp[j * 4 + 2], B3 = Bp[j * 4 + 3];
    const float du = d * u;
    float Bv[NDS];
    #pragma unroll
    for (int e = 0; e < 4; ++e) {
      Bv[e] = B0[e]; Bv[4 + e] = B1[e]; Bv[8 + e] = B2[e]; Bv[12 + e] = B3[e];
    }
    #pragma unroll
    for (int s = 0; s < NDS; ++s) {
      float dA = __expf(d * Av[s]);
      h[s] = dA * h[s] + du * Bv[s];
    }
    float sum01 = 0.f, sum23 = 0.f;
    #pragma unroll
    for (int s = 0; s < 8; ++s)  sum01 += h[s];
    #pragma unroll
    for (int s = 8; s < 16; ++s) sum23 += h[s];
    float y = sum01 + sum23 + u * dcoef;
    float z = zp[(size_t)j * (2 * NDI)];
    y *= z / (1.f + __expf(-z));
    ylds[j & 15][tid] = y;

    if ((j & 15) == 15) {               // drain slab: 16 t x 256 c -> FG
      __syncthreads();
      const int jb = j - 15;
      #pragma unroll
      for (int s2 = 0; s2 < 2; ++s2) {
        int u2 = tid + 256 * s2;
        int tt = u2 & 15, q = u2 >> 4;  // rr-minor -> contiguous 16B chunks
        short8 v;
        #pragma unroll
        for (int e = 0; e < 8; ++e) v[e] = f2bf(ylds[tt][q * 8 + e]);
        int grow = b * NL + t0 + jb + tt;
        int k8 = (cb0 >> 3) + q;
        *(short8*)&ybf[fgoff(grow, k8, NDI)] = v;
      }
      __syncthreads();
    }
  }
}

// ---------------------------------------------------------------------------
extern "C" void kernel_launch(void* const* d_in, const int* in_sizes, int n_in,
                              void* d_out, int out_size, void* d_ws, size_t ws_size,
                              hipStream_t stream) {
  const float* x      = (const float*)d_in[0];
  const float* W_in   = (const float*)d_in[1];
  const float* b_in   = (const float*)d_in[2];
  const float* conv_w = (const float*)d_in[3];
  const float* conv_b = (const float*)d_in[4];
  const float* W_x    = (const float*)d_in[5];
  const float* b_x    = (const float*)d_in[6];
  const float* W_dt   = (const float*)d_in[7];
  const float* b_dt   = (const float*)d_in[8];
  const float* A_log  = (const float*)d_in[9];
  const float* Dv     = (const float*)d_in[10];
  const float* W_out  = (const float*)d_in[11];
  const float* b_out  = (const float*)d_in[12];
  float* out = (float*)d_out;

  char* w = (char*)d_ws;
  short* xbf   = (short*)(w);                  // FG 4096x1024 bf16   8.39MB
  short* WtIn  = (short*)(w + 8388608);        // FG 4096x1024 bf16   8.39MB
  short* WtDt  = (short*)(w + 16777216);       // FG 2048x2048 bf16   8.39MB
  short* WtOut = (short*)(w + 25165824);       // FG 1024x2048 bf16   4.19MB
  float* xz    = (float*)(w + 29360128);       // 4096x4096 f32      67.1MB
  float* xhf   = (float*)(w + 96468992);       // 4096x2048 f32      33.6MB
  short* xhbf  = (short*)(w + 130023424);      // FG 4096x2048 bf16  16.8MB
  float* delta = (float*)(w + 146800640);      // 4096x2048 f32      33.6MB
  float* Bm    = (float*)(w + 180355072);      // 4096x16   f32       0.26MB
  short* ybf   = (short*)(w + 214171648);      // FG 4096x2048 bf16  16.8MB
  // scan scratch aliases buffers dead by scan time (8.39MB each, CCH=32):
  float* Pbuf  = (float*)(w);                  // aliases xbf
  float* Hend  = (float*)(w + 8388608);        // aliases WtIn
  float* Hin   = (float*)(w + 16777216);       // aliases WtDt

  // 1) converts / weight transposes into FG layout
  cvt_fg_kernel<<<MROWS / 16, 256, 0, stream>>>(x, xbf);
  transpose_fg_kernel<<<dim3((2 * NDI) / 32, NDM / 64), dim3(32, 8), 0, stream>>>(
      W_in, WtIn, NDM, 2 * NDI);
  transpose_fg_kernel<<<dim3(NDI / 32, NDI / 64), dim3(32, 8), 0, stream>>>(
      W_dt, WtDt, NDI, NDI);
  transpose_fg_kernel<<<dim3(NDM / 32, NDI / 64), dim3(32, 8), 0, stream>>>(
      W_out, WtOut, NDI, NDM);

  // 2) xz = x @ W_in + b_in   (32x32 = 1024 blocks)
  gemm_fg_kernel<128, 0><<<dim3((2 * NDI) / 128, MROWS / 128), 256, 0, stream>>>(
      xbf, WtIn, b_in, xz, MROWS, 2 * NDI, NDM);

  // 3) depthwise conv + silu (slab; writes xhf row-major + xhbf FG)
  conv_silu_kernel<<<dim3(NDI / 512, MROWS / 16), 256, 0, stream>>>(
      xz, conv_w, conv_b, xhf, xhbf);

  // 4) Bmat = xh @ W_x[:,16:32] + b_x[16:32]
  bmat_kernel<<<MROWS / 4, 256, 0, stream>>>(xhf, W_x, b_x, Bm);

  // 5) delta = softplus(xh @ W_dt + b_dt)   (16x32 = 512 blocks)
  gemm_fg_kernel<128, 1><<<dim3(NDI / 128, MROWS / 128), 256, 0, stream>>>(
      xhbf, WtDt, b_dt, delta, MROWS, NDI, NDI);

  // 6) selective scan (chunked: local scan -> chunk combine -> rescan+merge)
  scan_p1_kernel<<<(NB * NDI * CCH) / 256, 256, 0, stream>>>(
      delta, Bm, xhf, A_log, Pbuf, Hend);
  scan_p2_kernel<<<(NB * NDI * NDS) / 256, 256, 0, stream>>>(Pbuf, Hend, Hin);
  scan_p3_kernel<<<(NB * NDI * CCH) / 256, 256, 0, stream>>>(
      delta, Bm, xhf, A_log, Hin, Dv, xz, ybf);

  // 7) out = y @ W_out + b_out   (BN=64: 16x32 = 512 blocks)
  gemm_fg_kernel<64, 0><<<dim3(NDM / 64, MROWS / 128), 256, 0, stream>>>(
      ybf, WtOut, b_out, out, MROWS, NDM, NDI);
}

// Round 13
// 327.391 us; speedup vs baseline: 1.0626x; 1.0626x over previous
//
#include <hip/hip_runtime.h>
#include <stdint.h>

// Problem constants
#define NDM   1024   // D_MODEL
#define NDS   16     // D_STATE
#define NDC   4      // D_CONV
#define NDI   2048   // D_INNER
#define NB    2      // BATCH
#define NL    2048   // SEQ
#define MROWS (NB*NL)   // 4096
#define CCH   32     // scan chunks
#define CLEN  64     // NL / CCH

typedef __bf16 bf16x8 __attribute__((ext_vector_type(8)));
typedef float  f32x4  __attribute__((ext_vector_type(4)));
typedef short  short8 __attribute__((ext_vector_type(8)));

__device__ __forceinline__ short f2bf(float f) {
  union { float f; unsigned u; } x; x.f = f;
  unsigned r = (x.u + 0x7FFFu + ((x.u >> 16) & 1u)) >> 16;
  return (short)r;
}
__device__ __forceinline__ float bf2f(short s) {
  union { unsigned u; float f; } x; x.u = ((unsigned)(unsigned short)s) << 16;
  return x.f;
}

// Fragment-order Global layout (FG): 16-row groups; chunk (k8, r) of 8 shorts
// at k8*128 + (r&15)*8. A 16x32 MFMA fragment = CONTIGUOUS 1KB in lane order.
__device__ __forceinline__ size_t fgoff(int row, int k8, int K) {
  return (size_t)(row >> 4) * K * 16 + (size_t)k8 * 128 + (row & 15) * 8;
}

// ---------------------------------------------------------------------------
// x (f32, MROWS x 1024 row-major) -> FG bf16 via LDS slab
__global__ __launch_bounds__(256) void cvt_fg_kernel(
    const float* __restrict__ in, short* __restrict__ out) {
  __shared__ short slab[16][1032];
  const int tid = threadIdx.x;
  const int g = blockIdx.x;
  const float* p = in + (size_t)g * 16 * 1024;
  #pragma unroll
  for (int u = 0; u < 8; ++u) {
    int unit = u * 256 + tid;
    int rr = unit >> 7, cc = unit & 127;
    const float* rp = p + (size_t)rr * 1024 + cc * 8;
    #pragma unroll
    for (int e = 0; e < 8; ++e) slab[rr][cc * 8 + e] = f2bf(rp[e]);
  }
  __syncthreads();
  short* op = out + (size_t)g * 16384;
  #pragma unroll
  for (int u = 0; u < 8; ++u) {
    int u2 = u * 256 + tid;
    int rr = u2 & 15, k8 = u2 >> 4;
    *(short8*)&op[k8 * 128 + rr * 8] = *(short8*)&slab[rr][k8 * 8];
  }
}

// ---------------------------------------------------------------------------
// W (K x N f32) -> FG bf16 of W^T (N rows, K cols). 32n x 64k tiles.
__global__ __launch_bounds__(256) void transpose_fg_kernel(
    const float* __restrict__ in, short* __restrict__ out, int K, int N) {
  __shared__ float t[64][33];
  const int tx = threadIdx.x, ty = threadIdx.y;   // 32, 8
  const int n0 = blockIdx.x * 32, k0 = blockIdx.y * 64;
  #pragma unroll
  for (int i = 0; i < 64; i += 8)
    t[ty + i][tx] = in[(size_t)(k0 + ty + i) * N + n0 + tx];
  __syncthreads();
  const int n = n0 + tx, k8 = (k0 >> 3) + ty;
  short8 v;
  #pragma unroll
  for (int e = 0; e < 8; ++e) v[e] = f2bf(t[ty * 8 + e][tx]);
  *(short8*)&out[fgoff(n, k8, K)] = v;
}

// ---------------------------------------------------------------------------
// W_x cols 16..31 -> FG rows 2048..2063 of Wcat (group 128). K=2048.
__global__ __launch_bounds__(256) void wx_fg_kernel(
    const float* __restrict__ Wx, short* __restrict__ Wcat) {
  int t = blockIdx.x * 256 + threadIdx.x;     // 4096 = 256 k8 x 16 n
  int k8 = t >> 4, n = t & 15;
  short8 v;
  #pragma unroll
  for (int e = 0; e < 8; ++e)
    v[e] = f2bf(Wx[(size_t)(k8 * 8 + e) * (2 * NDS) + NDS + n]);
  *(short8*)&Wcat[(size_t)128 * 2048 * 16 + (size_t)k8 * 128 + n * 8] = v;
}

// ---------------------------------------------------------------------------
// Register-direct FG bf16 TN GEMM (no LDS staging, no barriers in K-loop).
// EPI=0: f32 C + bias (gemm-out)
// EPI=1: delta = softplus(v + bias) for cols<2048; cols 2048..2063 -> Bm+bx
// EPI=2: bf16 row-major C via LDS tile (xz output)
template<int BN, int EPI>
__global__ __launch_bounds__(256, 2) void gemm_fg_kernel(
    const short* __restrict__ A, const short* __restrict__ Bt,
    const float* __restrict__ bias, float* __restrict__ C,
    short* __restrict__ Cb, float* __restrict__ Bm,
    const float* __restrict__ bx, int M, int N, int K)
{
  const int tid  = threadIdx.x;
  const int lane = tid & 63;
  const int w    = tid >> 6;
  const int wM   = w >> 1;
  const int wN   = w & 1;
  const int g    = lane >> 4;
  const int r    = lane & 15;

  constexpr int FN = BN / 32;

  // XCD-aware swizzle (all our grids have nwg % 8 == 0)
  const int nx  = gridDim.x;
  const int nwg = nx * gridDim.y;
  const int bid = blockIdx.y * nx + blockIdx.x;
  const int swz = (bid & 7) * (nwg >> 3) + (bid >> 3);
  const int bm  = (swz / nx) * 128;
  const int bn  = (swz % nx) * BN;

  const short* pA[4];
  const short* pB[FN];
  #pragma unroll
  for (int m = 0; m < 4; ++m)
    pA[m] = A + (size_t)((bm >> 4) + wM * 4 + m) * K * 16 + lane * 8;
  #pragma unroll
  for (int n = 0; n < FN; ++n)
    pB[n] = Bt + (size_t)((bn >> 4) + wN * FN + n) * K * 16 + lane * 8;

  f32x4 acc[4][FN];
  #pragma unroll
  for (int m = 0; m < 4; ++m)
    #pragma unroll
    for (int n = 0; n < FN; ++n)
      acc[m][n] = (f32x4){0.f, 0.f, 0.f, 0.f};

  bf16x8 a0[4], b0[FN], a1[4], b1[FN];
  #pragma unroll
  for (int m = 0; m < 4; ++m) a0[m] = *(const bf16x8*)(pA[m]);
  #pragma unroll
  for (int n = 0; n < FN; ++n) b0[n] = *(const bf16x8*)(pB[n]);

  for (int kb = 0; kb < K; kb += 64) {
    if (kb + 32 < K) {
      #pragma unroll
      for (int m = 0; m < 4; ++m)
        a1[m] = *(const bf16x8*)(pA[m] + (size_t)(kb + 32) * 16);
      #pragma unroll
      for (int n = 0; n < FN; ++n)
        b1[n] = *(const bf16x8*)(pB[n] + (size_t)(kb + 32) * 16);
    }
    #pragma unroll
    for (int m = 0; m < 4; ++m)
      #pragma unroll
      for (int n = 0; n < FN; ++n)
        acc[m][n] = __builtin_amdgcn_mfma_f32_16x16x32_bf16(
            a0[m], b0[n], acc[m][n], 0, 0, 0);

    if (kb + 64 < K) {
      #pragma unroll
      for (int m = 0; m < 4; ++m)
        a0[m] = *(const bf16x8*)(pA[m] + (size_t)(kb + 64) * 16);
      #pragma unroll
      for (int n = 0; n < FN; ++n)
        b0[n] = *(const bf16x8*)(pB[n] + (size_t)(kb + 64) * 16);
    }
    #pragma unroll
    for (int m = 0; m < 4; ++m)
      #pragma unroll
      for (int n = 0; n < FN; ++n)
        acc[m][n] = __builtin_amdgcn_mfma_f32_16x16x32_bf16(
            a1[m], b1[n], acc[m][n], 0, 0, 0);
  }

  // D layout (verified m89/m91): col = lane&15, row = (lane>>4)*4 + e
  if constexpr (EPI == 2) {
    // bf16 row-major epilogue via LDS tile (coalesced 256B row segments)
    __shared__ short ctile[128][136];
    #pragma unroll
    for (int m = 0; m < 4; ++m) {
      const int rl0 = wM * 64 + m * 16 + g * 4;
      #pragma unroll
      for (int n = 0; n < FN; ++n) {
        const int cl = wN * (BN / 2) + n * 16 + r;
        const float bv = bias[bn + cl];
        #pragma unroll
        for (int e = 0; e < 4; ++e)
          ctile[rl0 + e][cl] = f2bf(acc[m][n][e] + bv);
      }
    }
    __syncthreads();
    #pragma unroll
    for (int it = 0; it < (128 * BN / 8) / 256; ++it) {
      int id = it * 256 + tid;
      int rowL = id / (BN / 8), c8 = id % (BN / 8);
      *(short8*)&Cb[(size_t)(bm + rowL) * N + bn + c8 * 8] =
          *(short8*)&ctile[rowL][c8 * 8];
    }
  } else {
    #pragma unroll
    for (int m = 0; m < 4; ++m) {
      const int row0 = bm + wM * 64 + m * 16 + g * 4;
      #pragma unroll
      for (int n = 0; n < FN; ++n) {
        const int colbase = bn + wN * (BN / 2) + n * 16;
        const int col = colbase + r;
        if (EPI == 0 || colbase < 2048) {
          const float bv = bias[col];
          #pragma unroll
          for (int e = 0; e < 4; ++e) {
            float v = acc[m][n][e] + bv;
            if (EPI == 1) v = (v > 15.f) ? v : log1pf(__expf(v));
            C[(size_t)(row0 + e) * N + col] = v;
          }
        } else if (EPI == 1 && colbase < 2064) {
          const float bv = bx[NDS + r];
          #pragma unroll
          for (int e = 0; e < 4; ++e)
            Bm[(size_t)(row0 + e) * NDS + r] = acc[m][n][e] + bv;
        }
      }
    }
  }
}

// ---------------------------------------------------------------------------
// depthwise causal conv (width 4) + bias + SiLU; reads bf16 xz, slab version.
__global__ __launch_bounds__(256) void conv_silu_kernel(
    const short* __restrict__ xz, const float* __restrict__ cw,
    const float* __restrict__ cb, float* __restrict__ xh,
    short* __restrict__ xhbf) {
  __shared__ short slab[16][528];
  const int tid = threadIdx.x;
  const int c0 = blockIdx.x * 512;
  const int r0 = blockIdx.y * 16;
  const int b  = r0 >> 11;
  const int t0 = r0 & (NL - 1);
  const short* zbase = xz + ((size_t)b * NL) * (2 * NDI);

  #pragma unroll
  for (int u = 0; u < 4; ++u) {
    int unit = u * 256 + tid;
    int rr = unit >> 6, cc = unit & 63;
    int t = t0 + rr, c = c0 + cc * 8;
    float acc[8];
    #pragma unroll
    for (int e = 0; e < 8; ++e) acc[e] = cb[c + e];
    #pragma unroll
    for (int k = 0; k < NDC; ++k) {
      int tt = t - (NDC - 1) + k;
      if (tt >= 0) {
        short8 rv = *(const short8*)(zbase + (size_t)tt * (2 * NDI) + c);
        #pragma unroll
        for (int e = 0; e < 8; ++e)
          acc[e] += cw[(c + e) * NDC + k] * bf2f(rv[e]);
      }
    }
    float* xo = xh + (size_t)(r0 + rr) * NDI + c;
    #pragma unroll
    for (int e = 0; e < 8; ++e) {
      float s = acc[e] / (1.f + __expf(-acc[e]));
      xo[e] = s;
      slab[rr][cc * 8 + e] = f2bf(s);
    }
  }
  __syncthreads();
  short* op = xhbf + (size_t)(r0 >> 4) * NDI * 16 + (size_t)(c0 >> 3) * 128;
  #pragma unroll
  for (int u = 0; u < 4; ++u) {
    int u2 = u * 256 + tid;
    int rr = u2 & 15, q = u2 >> 4;
    *(short8*)&op[q * 128 + rr * 8] = *(short8*)&slab[rr][q * 8];
  }
}

// ---------------------------------------------------------------------------
// scan scratch layout: [b][k][c][s]
__device__ __forceinline__ size_t scoff(int b, int k, int c) {
  return (((size_t)b * CCH + k) * NDI + c) * NDS;
}

// phase 1: thread = (b, c, chunk); 16 states in registers.
__global__ __launch_bounds__(256) void scan_p1_kernel(
    const float* __restrict__ delta, const float* __restrict__ Bm,
    const float* __restrict__ xh, const float* __restrict__ A_log,
    float* __restrict__ Pbuf, float* __restrict__ Hend) {
  const int i = blockIdx.x * 256 + threadIdx.x;
  const int c = i & (NDI - 1);
  const int k = (i >> 11) & (CCH - 1);
  const int b = i >> 16;
  const int t0 = k * CLEN;

  float Av[NDS];
  #pragma unroll
  for (int s = 0; s < NDS; ++s) Av[s] = -__expf(A_log[c * NDS + s]);

  const float* dp = delta + ((size_t)(b * NL + t0)) * NDI + c;
  const float* up = xh    + ((size_t)(b * NL + t0)) * NDI + c;
  const f32x4* Bp = (const f32x4*)(Bm + ((size_t)(b * NL + t0)) * NDS);

  float h[NDS], P[NDS];
  #pragma unroll
  for (int s = 0; s < NDS; ++s) { h[s] = 0.f; P[s] = 1.f; }

  #pragma unroll 4
  for (int j = 0; j < CLEN; ++j) {
    const float d = dp[(size_t)j * NDI];
    const float u = up[(size_t)j * NDI];
    f32x4 B0 = Bp[j * 4 + 0], B1 = Bp[j * 4 + 1];
    f32x4 B2 = Bp[j * 4 + 2], B3 = Bp[j * 4 + 3];
    const float du = d * u;
    float Bv[NDS];
    #pragma unroll
    for (int e = 0; e < 4; ++e) {
      Bv[e] = B0[e]; Bv[4 + e] = B1[e]; Bv[8 + e] = B2[e]; Bv[12 + e] = B3[e];
    }
    #pragma unroll
    for (int s = 0; s < NDS; ++s) {
      float dA = __expf(d * Av[s]);
      h[s] = dA * h[s] + du * Bv[s];
      P[s] *= dA;
    }
  }

  const size_t base = scoff(b, k, c);
  #pragma unroll
  for (int q = 0; q < 4; ++q) {
    *(f32x4*)&Pbuf[base + q * 4] = (f32x4){P[q*4], P[q*4+1], P[q*4+2], P[q*4+3]};
    *(f32x4*)&Hend[base + q * 4] = (f32x4){h[q*4], h[q*4+1], h[q*4+2], h[q*4+3]};
  }
}

// ---------------------------------------------------------------------------
// phase 2: thread = (b, c, s); serial combine across the chunks.
__global__ __launch_bounds__(256) void scan_p2_kernel(
    const float* __restrict__ Pbuf, const float* __restrict__ Hend,
    float* __restrict__ Hin) {
  const int i = blockIdx.x * 256 + threadIdx.x;
  const int s = i & (NDS - 1);
  const int c = (i >> 4) & (NDI - 1);
  const int b = i >> 15;
  const size_t step = (size_t)NDI * NDS;
  const size_t base = scoff(b, 0, c) + s;
  float h = 0.f;
  #pragma unroll 8
  for (int k = 0; k < CCH; ++k) {
    Hin[base + (size_t)k * step] = h;
    h = Hend[base + (size_t)k * step] + Pbuf[base + (size_t)k * step] * h;
  }
}

// ---------------------------------------------------------------------------
// phase 3 + merge: rescan; y = (sum_s h + u*D) * silu(z); z from bf16 xz;
// LDS slab-transpose -> FG bf16 output.
__global__ __launch_bounds__(256) void scan_p3_kernel(
    const float* __restrict__ delta, const float* __restrict__ Bm,
    const float* __restrict__ xh, const float* __restrict__ A_log,
    const float* __restrict__ Hin, const float* __restrict__ Dvec,
    const short* __restrict__ xz, short* __restrict__ ybf) {
  const int tid = threadIdx.x;
  const int i = blockIdx.x * 256 + tid;
  const int c = i & (NDI - 1);
  const int k = (i >> 11) & (CCH - 1);
  const int b = i >> 16;
  const int t0 = k * CLEN;
  const int cb0 = (blockIdx.x * 256) & (NDI - 1);

  __shared__ float ylds[16][257];

  float Av[NDS];
  #pragma unroll
  for (int s = 0; s < NDS; ++s) Av[s] = -__expf(A_log[c * NDS + s]);
  const float dcoef = Dvec[c];

  const float* dp = delta + ((size_t)(b * NL + t0)) * NDI + c;
  const float* up = xh    + ((size_t)(b * NL + t0)) * NDI + c;
  const f32x4* Bp = (const f32x4*)(Bm + ((size_t)(b * NL + t0)) * NDS);
  const short* zp = xz    + ((size_t)(b * NL + t0)) * (2 * NDI) + NDI + c;

  const size_t base = scoff(b, k, c);
  float h[NDS];
  #pragma unroll
  for (int s = 0; s < NDS; ++s) h[s] = Hin[base + s];

  for (int j = 0; j < CLEN; ++j) {
    const float d = dp[(size_t)j * NDI];
    const float u = up[(size_t)j * NDI];
    f32x4 B0 = Bp[j * 4 + 0], B1 = Bp[j * 4 + 1];
    f32x4 B2 = Bp[j * 4 + 2], B3 = Bp[j * 4 + 3];
    const float du = d * u;
    float Bv[NDS];
    #pragma unroll
    for (int e = 0; e < 4; ++e) {
      Bv[e] = B0[e]; Bv[4 + e] = B1[e]; Bv[8 + e] = B2[e]; Bv[12 + e] = B3[e];
    }
    #pragma unroll
    for (int s = 0; s < NDS; ++s) {
      float dA = __expf(d * Av[s]);
      h[s] = dA * h[s] + du * Bv[s];
    }
    float sum01 = 0.f, sum23 = 0.f;
    #pragma unroll
    for (int s = 0; s < 8; ++s)  sum01 += h[s];
    #pragma unroll
    for (int s = 8; s < 16; ++s) sum23 += h[s];
    float y = sum01 + sum23 + u * dcoef;
    float z = bf2f(zp[(size_t)j * (2 * NDI)]);
    y *= z / (1.f + __expf(-z));
    ylds[j & 15][tid] = y;

    if ((j & 15) == 15) {
      __syncthreads();
      const int jb = j - 15;
      #pragma unroll
      for (int s2 = 0; s2 < 2; ++s2) {
        int u2 = tid + 256 * s2;
        int tt = u2 & 15, q = u2 >> 4;
        short8 v;
        #pragma unroll
        for (int e = 0; e < 8; ++e) v[e] = f2bf(ylds[tt][q * 8 + e]);
        int grow = b * NL + t0 + jb + tt;
        int k8 = (cb0 >> 3) + q;
        *(short8*)&ybf[fgoff(grow, k8, NDI)] = v;
      }
      __syncthreads();
    }
  }
}

// ---------------------------------------------------------------------------
extern "C" void kernel_launch(void* const* d_in, const int* in_sizes, int n_in,
                              void* d_out, int out_size, void* d_ws, size_t ws_size,
                              hipStream_t stream) {
  const float* x      = (const float*)d_in[0];
  const float* W_in   = (const float*)d_in[1];
  const float* b_in   = (const float*)d_in[2];
  const float* conv_w = (const float*)d_in[3];
  const float* conv_b = (const float*)d_in[4];
  const float* W_x    = (const float*)d_in[5];
  const float* b_x    = (const float*)d_in[6];
  const float* W_dt   = (const float*)d_in[7];
  const float* b_dt   = (const float*)d_in[8];
  const float* A_log  = (const float*)d_in[9];
  const float* Dv     = (const float*)d_in[10];
  const float* W_out  = (const float*)d_in[11];
  const float* b_out  = (const float*)d_in[12];
  float* out = (float*)d_out;

  char* w = (char*)d_ws;
  short* xbf   = (short*)(w);                  // FG 4096x1024 bf16   8.39MB
  short* WtIn  = (short*)(w + 8388608);        // FG 4096x1024 bf16   8.39MB
  short* WtCat = (short*)(w + 16777216);       // FG 2176x2048 bf16   8.91MB
  short* WtOut = (short*)(w + 25690112);       // FG 1024x2048 bf16   4.19MB
  short* xzbf  = (short*)(w + 29884416);       // 4096x4096 bf16     33.55MB
  float* xhf   = (float*)(w + 63438848);       // 4096x2048 f32      33.55MB
  short* xhbf  = (short*)(w + 96993280);       // FG 4096x2048 bf16  16.78MB
  float* delta = (float*)(w + 113770496);      // 4096x2048 f32      33.55MB
  float* Bm    = (float*)(w + 147324928);      // 4096x16   f32       0.26MB
  short* ybf   = (short*)(w + 147587072);      // FG 4096x2048 bf16  16.78MB
  // scan scratch aliases buffers dead by scan time (8.39MB each):
  float* Pbuf  = (float*)(w);                  // aliases xbf
  float* Hend  = (float*)(w + 8388608);        // aliases WtIn
  float* Hin   = (float*)(w + 16777216);       // aliases WtCat head

  // 0) zero Wcat pad groups 129..135 (rows 2064..2175) once per call
  hipMemsetAsync((char*)WtCat + (size_t)129 * 65536, 0, 7 * 65536, stream);

  // 1) converts / weight transposes into FG layout
  cvt_fg_kernel<<<MROWS / 16, 256, 0, stream>>>(x, xbf);
  transpose_fg_kernel<<<dim3((2 * NDI) / 32, NDM / 64), dim3(32, 8), 0, stream>>>(
      W_in, WtIn, NDM, 2 * NDI);
  transpose_fg_kernel<<<dim3(NDI / 32, NDI / 64), dim3(32, 8), 0, stream>>>(
      W_dt, WtCat, NDI, NDI);
  wx_fg_kernel<<<16, 256, 0, stream>>>(W_x, WtCat);
  transpose_fg_kernel<<<dim3(NDM / 32, NDI / 64), dim3(32, 8), 0, stream>>>(
      W_out, WtOut, NDI, NDM);

  // 2) xz = x @ W_in + b_in -> bf16 row-major (EPI=2)
  gemm_fg_kernel<128, 2><<<dim3((2 * NDI) / 128, MROWS / 128), 256, 0, stream>>>(
      xbf, WtIn, b_in, nullptr, xzbf, nullptr, nullptr,
      MROWS, 2 * NDI, NDM);

  // 3) depthwise conv + silu (reads bf16 xz; writes xhf f32 + xhbf FG)
  conv_silu_kernel<<<dim3(NDI / 512, MROWS / 16), 256, 0, stream>>>(
      xzbf, conv_w, conv_b, xhf, xhbf);

  // 4+5) fused: [delta | Bmat] = xh @ [W_dt | W_x[:,16:32]] (EPI=1, N=2176)
  gemm_fg_kernel<128, 1><<<dim3(2176 / 128, MROWS / 128), 256, 0, stream>>>(
      xhbf, WtCat, b_dt, delta, nullptr, Bm, b_x,
      MROWS, NDI, NDI);

  // 6) selective scan (chunked: local scan -> chunk combine -> rescan+merge)
  scan_p1_kernel<<<(NB * NDI * CCH) / 256, 256, 0, stream>>>(
      delta, Bm, xhf, A_log, Pbuf, Hend);
  scan_p2_kernel<<<(NB * NDI * NDS) / 256, 256, 0, stream>>>(Pbuf, Hend, Hin);
  scan_p3_kernel<<<(NB * NDI * CCH) / 256, 256, 0, stream>>>(
      delta, Bm, xhf, A_log, Hin, Dv, xzbf, ybf);

  // 7) out = y @ W_out + b_out  (EPI=0, BN=64)
  gemm_fg_kernel<64, 0><<<dim3(NDM / 64, MROWS / 128), 256, 0, stream>>>(
      ybf, WtOut, b_out, out, nullptr, nullptr, nullptr,
      MROWS, NDM, NDI);
}

// Round 15
// 326.791 us; speedup vs baseline: 1.0646x; 1.0018x over previous
//
#include <hip/hip_runtime.h>
#include <stdint.h>

// Problem constants
#define NDM   1024   // D_MODEL
#define NDS   16     // D_STATE
#define NDC   4      // D_CONV
#define NDI   2048   // D_INNER
#define NB    2      // BATCH
#define NL    2048   // SEQ
#define MROWS (NB*NL)   // 4096
#define CCH   32     // scan chunks
#define CLEN  64     // NL / CCH

typedef __bf16 bf16x8 __attribute__((ext_vector_type(8)));
typedef float  f32x4  __attribute__((ext_vector_type(4)));
typedef short  short8 __attribute__((ext_vector_type(8)));

__device__ __forceinline__ short f2bf(float f) {
  union { float f; unsigned u; } x; x.f = f;
  unsigned r = (x.u + 0x7FFFu + ((x.u >> 16) & 1u)) >> 16;
  return (short)r;
}
__device__ __forceinline__ float bf2f(short s) {
  union { unsigned u; float f; } x; x.u = ((unsigned)(unsigned short)s) << 16;
  return x.f;
}

// Fragment-order Global layout (FG): 16-row groups; chunk (k8, r) of 8 shorts
// at k8*128 + (r&15)*8. A 16x32 MFMA fragment = CONTIGUOUS 1KB in lane order.
__device__ __forceinline__ size_t fgoff(int row, int k8, int K) {
  return (size_t)(row >> 4) * K * 16 + (size_t)k8 * 128 + (row & 15) * 8;
}

__device__ __forceinline__ void gload16(const void* g, void* l) {
  __builtin_amdgcn_global_load_lds(
      (__attribute__((address_space(1))) void*)(uintptr_t)g,
      (__attribute__((address_space(3))) void*)l,
      16, 0, 0);
}

// ---------------------------------------------------------------------------
// x (f32, MROWS x 1024 row-major) -> FG bf16 via LDS slab
__global__ __launch_bounds__(256) void cvt_fg_kernel(
    const float* __restrict__ in, short* __restrict__ out) {
  __shared__ short slab[16][1032];
  const int tid = threadIdx.x;
  const int g = blockIdx.x;
  const float* p = in + (size_t)g * 16 * 1024;
  #pragma unroll
  for (int u = 0; u < 8; ++u) {
    int unit = u * 256 + tid;
    int rr = unit >> 7, cc = unit & 127;
    const float* rp = p + (size_t)rr * 1024 + cc * 8;
    #pragma unroll
    for (int e = 0; e < 8; ++e) slab[rr][cc * 8 + e] = f2bf(rp[e]);
  }
  __syncthreads();
  short* op = out + (size_t)g * 16384;
  #pragma unroll
  for (int u = 0; u < 8; ++u) {
    int u2 = u * 256 + tid;
    int rr = u2 & 15, k8 = u2 >> 4;
    *(short8*)&op[k8 * 128 + rr * 8] = *(short8*)&slab[rr][k8 * 8];
  }
}

// ---------------------------------------------------------------------------
// W (K x N f32) -> FG bf16 of W^T (N rows, K cols). 32n x 64k tiles.
__global__ __launch_bounds__(256) void transpose_fg_kernel(
    const float* __restrict__ in, short* __restrict__ out, int K, int N) {
  __shared__ float t[64][33];
  const int tx = threadIdx.x, ty = threadIdx.y;   // 32, 8
  const int n0 = blockIdx.x * 32, k0 = blockIdx.y * 64;
  #pragma unroll
  for (int i = 0; i < 64; i += 8)
    t[ty + i][tx] = in[(size_t)(k0 + ty + i) * N + n0 + tx];
  __syncthreads();
  const int n = n0 + tx, k8 = (k0 >> 3) + ty;
  short8 v;
  #pragma unroll
  for (int e = 0; e < 8; ++e) v[e] = f2bf(t[ty * 8 + e][tx]);
  *(short8*)&out[fgoff(n, k8, K)] = v;
}

// ---------------------------------------------------------------------------
// W_x cols 16..31 -> FG rows 2048..2063 of Wcat (group 128). K=2048.
__global__ __launch_bounds__(256) void wx_fg_kernel(
    const float* __restrict__ Wx, short* __restrict__ Wcat) {
  int t = blockIdx.x * 256 + threadIdx.x;     // 4096 = 256 k8 x 16 n
  int k8 = t >> 4, n = t & 15;
  short8 v;
  #pragma unroll
  for (int e = 0; e < 8; ++e)
    v[e] = f2bf(Wx[(size_t)(k8 * 8 + e) * (2 * NDS) + NDS + n]);
  *(short8*)&Wcat[(size_t)128 * 2048 * 16 + (size_t)k8 * 128 + n * 8] = v;
}

// ---------------------------------------------------------------------------
// FG bf16 TN GEMM, 256-row block tile: C = A_fg(MxK) * B_fg(NxK)^T + bias.
// BM=256 fixed, BN in {64,128}. 8 waves (2M x 4N), per-wave 128 x BN/4,
// BK=32, LDS double-buffer, one __syncthreads per K-step, prefetch after
// barrier. Cuts per-block operand traffic ~1.5-2x vs the 128-tile whose
// (1/BM+1/BN) L2-traffic wall was the measured ~470 TF ceiling (R13).
// EPI=0: f32 C + bias (gemm-out)
// EPI=1: delta = softplus(v + bias) cols<2048; cols 2048..2063 -> Bm + bx
// EPI=2: bf16 row-major C via pool-aliased 256x136 LDS ctile (xz output)
template<int BN, int EPI>
__global__ __launch_bounds__(512, 2) void gemm_fg_kernel(
    const short* __restrict__ A, const short* __restrict__ Bt,
    const float* __restrict__ bias, float* __restrict__ C,
    short* __restrict__ Cb, float* __restrict__ Bm,
    const float* __restrict__ bx, int M, int N, int K)
{
  const int tid  = threadIdx.x;
  const int lane = tid & 63;
  const int w    = tid >> 6;      // wave 0..7
  const int wM   = w >> 2;        // 0..1
  const int wN   = w & 3;         // 0..3
  const int g    = lane >> 4;
  const int r    = lane & 15;

  constexpr int FNB  = BN / 64;       // B frags per wave (2 or 1)
  constexpr int NBG  = BN / 16;       // B groups per tile (8 or 4)
  constexpr int ABUF = 8192;          // A tile shorts (16 frags x 512)
  constexpr int BBUF = BN * 32;       // B tile shorts
  constexpr int STG  = 2 * (ABUF + BBUF);
  constexpr int POOL = (EPI == 2 && STG < 256 * 136) ? 256 * 136 : STG;
  __shared__ short pool[POOL];
  // LDS sub-buffer offsets computed at use (no pointer-array static init —
  // addrspacecast in static initializers doesn't compile on gfx950).
#define BUFA(b) (pool + (b) * (ABUF + BBUF))
#define BUFB(b) (pool + ABUF + (b) * (ABUF + BBUF))

  // XCD-aware swizzle (all grids have nwg % 8 == 0)
  const int nx  = gridDim.x;
  const int nwg = nx * gridDim.y;
  const int bid = blockIdx.y * nx + blockIdx.x;
  const int swz = (bid & 7) * (nwg >> 3) + (bid >> 3);
  const int bm  = (swz / nx) * 256;
  const int bn  = (swz % nx) * BN;

  const short* pA[2];
  #pragma unroll
  for (int q = 0; q < 2; ++q)
    pA[q] = A + (size_t)((bm >> 4) + 2 * w + q) * K * 16 + lane * 8;
  const short* pB =
      Bt + (size_t)((bn >> 4) + (w < NBG ? w : 0)) * K * 16 + lane * 8;

#define STAGE(buf, kb)                                                   \
  do {                                                                   \
    _Pragma("unroll")                                                    \
    for (int q = 0; q < 2; ++q)                                          \
      gload16(pA[q] + (size_t)(kb) * 16, BUFA(buf) + (2 * w + q) * 512 + \
              lane * 8 - lane * 8);                                      \
    if (w < NBG)                                                         \
      gload16(pB + (size_t)(kb) * 16, BUFB(buf) + w * 512);              \
  } while (0)

  // NOTE: gload16 LDS dest is wave-uniform base + lane*16 implicit; the
  // "+ lane*8 - lane*8" above keeps the expression wave-uniform explicitly.

  f32x4 acc[8][FNB];
  #pragma unroll
  for (int m = 0; m < 8; ++m)
    #pragma unroll
    for (int n = 0; n < FNB; ++n)
      acc[m][n] = (f32x4){0.f, 0.f, 0.f, 0.f};

  STAGE(0, 0);
  int cur = 0;
  for (int kb = 0; kb < K; kb += 32) {
    __syncthreads();                 // stages into cur visible; prev buf free
    if (kb + 32 < K) STAGE(cur ^ 1, kb + 32);   // prefetch under compute

    bf16x8 af[8], bfv[FNB];
    #pragma unroll
    for (int m = 0; m < 8; ++m)
      af[m] = *(const bf16x8*)(BUFA(cur) + (wM * 8 + m) * 512 + lane * 8);
    #pragma unroll
    for (int n = 0; n < FNB; ++n)
      bfv[n] = *(const bf16x8*)(BUFB(cur) + (wN * FNB + n) * 512 + lane * 8);

    #pragma unroll
    for (int m = 0; m < 8; ++m)
      #pragma unroll
      for (int n = 0; n < FNB; ++n)
        acc[m][n] = __builtin_amdgcn_mfma_f32_16x16x32_bf16(
            af[m], bfv[n], acc[m][n], 0, 0, 0);
    cur ^= 1;
  }
#undef STAGE
#undef BUFA
#undef BUFB

  // D layout (verified m89/m91): col = lane&15, row = (lane>>4)*4 + e
  if constexpr (EPI == 2) {
    __syncthreads();                 // staging reads done; reuse pool as ctile
    short (*ctile)[136] = (short(*)[136])pool;
    #pragma unroll
    for (int m = 0; m < 8; ++m) {
      const int rl0 = wM * 128 + m * 16 + g * 4;
      #pragma unroll
      for (int n = 0; n < FNB; ++n) {
        const int cl = wN * (BN / 4) + n * 16 + r;
        const float bv = bias[bn + cl];
        #pragma unroll
        for (int e = 0; e < 4; ++e)
          ctile[rl0 + e][cl] = f2bf(acc[m][n][e] + bv);
      }
    }
    __syncthreads();
    constexpr int CPR = BN / 8;      // 16B chunks per row
    #pragma unroll
    for (int it = 0; it < (256 * CPR) / 512; ++it) {
      int id = it * 512 + tid;
      int rowL = id / CPR, c8 = id % CPR;
      *(short8*)&Cb[(size_t)(bm + rowL) * N + bn + c8 * 8] =
          *(short8*)&ctile[rowL][c8 * 8];
    }
  } else {
    #pragma unroll
    for (int m = 0; m < 8; ++m) {
      const int row0 = bm + wM * 128 + m * 16 + g * 4;
      #pragma unroll
      for (int n = 0; n < FNB; ++n) {
        const int colbase = bn + wN * (BN / 4) + n * 16;
        const int col = colbase + r;
        if (EPI == 0 || colbase < 2048) {
          const float bv = bias[col];
          #pragma unroll
          for (int e = 0; e < 4; ++e) {
            float v = acc[m][n][e] + bv;
            if (EPI == 1) v = (v > 15.f) ? v : log1pf(__expf(v));
            C[(size_t)(row0 + e) * N + col] = v;
          }
        } else if (EPI == 1 && colbase < 2064) {
          const float bv = bx[NDS + r];
          #pragma unroll
          for (int e = 0; e < 4; ++e)
            Bm[(size_t)(row0 + e) * NDS + r] = acc[m][n][e] + bv;
        }
      }
    }
  }
}

// ---------------------------------------------------------------------------
// depthwise causal conv (width 4) + bias + SiLU; reads bf16 xz, slab version.
__global__ __launch_bounds__(256) void conv_silu_kernel(
    const short* __restrict__ xz, const float* __restrict__ cw,
    const float* __restrict__ cb, float* __restrict__ xh,
    short* __restrict__ xhbf) {
  __shared__ short slab[16][528];
  const int tid = threadIdx.x;
  const int c0 = blockIdx.x * 512;
  const int r0 = blockIdx.y * 16;
  const int b  = r0 >> 11;
  const int t0 = r0 & (NL - 1);
  const short* zbase = xz + ((size_t)b * NL) * (2 * NDI);

  #pragma unroll
  for (int u = 0; u < 4; ++u) {
    int unit = u * 256 + tid;
    int rr = unit >> 6, cc = unit & 63;
    int t = t0 + rr, c = c0 + cc * 8;
    float acc[8];
    #pragma unroll
    for (int e = 0; e < 8; ++e) acc[e] = cb[c + e];
    #pragma unroll
    for (int k = 0; k < NDC; ++k) {
      int tt = t - (NDC - 1) + k;
      if (tt >= 0) {
        short8 rv = *(const short8*)(zbase + (size_t)tt * (2 * NDI) + c);
        #pragma unroll
        for (int e = 0; e < 8; ++e)
          acc[e] += cw[(c + e) * NDC + k] * bf2f(rv[e]);
      }
    }
    float* xo = xh + (size_t)(r0 + rr) * NDI + c;
    #pragma unroll
    for (int e = 0; e < 8; ++e) {
      float s = acc[e] / (1.f + __expf(-acc[e]));
      xo[e] = s;
      slab[rr][cc * 8 + e] = f2bf(s);
    }
  }
  __syncthreads();
  short* op = xhbf + (size_t)(r0 >> 4) * NDI * 16 + (size_t)(c0 >> 3) * 128;
  #pragma unroll
  for (int u = 0; u < 4; ++u) {
    int u2 = u * 256 + tid;
    int rr = u2 & 15, q = u2 >> 4;
    *(short8*)&op[q * 128 + rr * 8] = *(short8*)&slab[rr][q * 8];
  }
}

// ---------------------------------------------------------------------------
// scan scratch layout: [b][k][c][s]
__device__ __forceinline__ size_t scoff(int b, int k, int c) {
  return (((size_t)b * CCH + k) * NDI + c) * NDS;
}

// phase 1: thread = (b, c, chunk); 16 states in registers.
__global__ __launch_bounds__(256) void scan_p1_kernel(
    const float* __restrict__ delta, const float* __restrict__ Bm,
    const float* __restrict__ xh, const float* __restrict__ A_log,
    float* __restrict__ Pbuf, float* __restrict__ Hend) {
  const int i = blockIdx.x * 256 + threadIdx.x;
  const int c = i & (NDI - 1);
  const int k = (i >> 11) & (CCH - 1);
  const int b = i >> 16;
  const int t0 = k * CLEN;

  float Av[NDS];
  #pragma unroll
  for (int s = 0; s < NDS; ++s) Av[s] = -__expf(A_log[c * NDS + s]);

  const float* dp = delta + ((size_t)(b * NL + t0)) * NDI + c;
  const float* up = xh    + ((size_t)(b * NL + t0)) * NDI + c;
  const f32x4* Bp = (const f32x4*)(Bm + ((size_t)(b * NL + t0)) * NDS);

  float h[NDS], P[NDS];
  #pragma unroll
  for (int s = 0; s < NDS; ++s) { h[s] = 0.f; P[s] = 1.f; }

  #pragma unroll 4
  for (int j = 0; j < CLEN; ++j) {
    const float d = dp[(size_t)j * NDI];
    const float u = up[(size_t)j * NDI];
    f32x4 B0 = Bp[j * 4 + 0], B1 = Bp[j * 4 + 1];
    f32x4 B2 = Bp[j * 4 + 2], B3 = Bp[j * 4 + 3];
    const float du = d * u;
    float Bv[NDS];
    #pragma unroll
    for (int e = 0; e < 4; ++e) {
      Bv[e] = B0[e]; Bv[4 + e] = B1[e]; Bv[8 + e] = B2[e]; Bv[12 + e] = B3[e];
    }
    #pragma unroll
    for (int s = 0; s < NDS; ++s) {
      float dA = __expf(d * Av[s]);
      h[s] = dA * h[s] + du * Bv[s];
      P[s] *= dA;
    }
  }

  const size_t base = scoff(b, k, c);
  #pragma unroll
  for (int q = 0; q < 4; ++q) {
    *(f32x4*)&Pbuf[base + q * 4] = (f32x4){P[q*4], P[q*4+1], P[q*4+2], P[q*4+3]};
    *(f32x4*)&Hend[base + q * 4] = (f32x4){h[q*4], h[q*4+1], h[q*4+2], h[q*4+3]};
  }
}

// ---------------------------------------------------------------------------
// phase 2: thread = (b, c, s); serial combine across the chunks.
__global__ __launch_bounds__(256) void scan_p2_kernel(
    const float* __restrict__ Pbuf, const float* __restrict__ Hend,
    float* __restrict__ Hin) {
  const int i = blockIdx.x * 256 + threadIdx.x;
  const int s = i & (NDS - 1);
  const int c = (i >> 4) & (NDI - 1);
  const int b = i >> 15;
  const size_t step = (size_t)NDI * NDS;
  const size_t base = scoff(b, 0, c) + s;
  float h = 0.f;
  #pragma unroll 8
  for (int k = 0; k < CCH; ++k) {
    Hin[base + (size_t)k * step] = h;
    h = Hend[base + (size_t)k * step] + Pbuf[base + (size_t)k * step] * h;
  }
}

// ---------------------------------------------------------------------------
// phase 3 + merge: rescan; y = (sum_s h + u*D) * silu(z); z from bf16 xz;
// LDS slab-transpose -> FG bf16 output.
__global__ __launch_bounds__(256) void scan_p3_kernel(
    const float* __restrict__ delta, const float* __restrict__ Bm,
    const float* __restrict__ xh, const float* __restrict__ A_log,
    const float* __restrict__ Hin, const float* __restrict__ Dvec,
    const short* __restrict__ xz, short* __restrict__ ybf) {
  const int tid = threadIdx.x;
  const int i = blockIdx.x * 256 + tid;
  const int c = i & (NDI - 1);
  const int k = (i >> 11) & (CCH - 1);
  const int b = i >> 16;
  const int t0 = k * CLEN;
  const int cb0 = (blockIdx.x * 256) & (NDI - 1);

  __shared__ float ylds[16][257];

  float Av[NDS];
  #pragma unroll
  for (int s = 0; s < NDS; ++s) Av[s] = -__expf(A_log[c * NDS + s]);
  const float dcoef = Dvec[c];

  const float* dp = delta + ((size_t)(b * NL + t0)) * NDI + c;
  const float* up = xh    + ((size_t)(b * NL + t0)) * NDI + c;
  const f32x4* Bp = (const f32x4*)(Bm + ((size_t)(b * NL + t0)) * NDS);
  const short* zp = xz    + ((size_t)(b * NL + t0)) * (2 * NDI) + NDI + c;

  const size_t base = scoff(b, k, c);
  float h[NDS];
  #pragma unroll
  for (int s = 0; s < NDS; ++s) h[s] = Hin[base + s];

  for (int j = 0; j < CLEN; ++j) {
    const float d = dp[(size_t)j * NDI];
    const float u = up[(size_t)j * NDI];
    f32x4 B0 = Bp[j * 4 + 0], B1 = Bp[j * 4 + 1];
    f32x4 B2 = Bp[j * 4 + 2], B3 = Bp[j * 4 + 3];
    const float du = d * u;
    float Bv[NDS];
    #pragma unroll
    for (int e = 0; e < 4; ++e) {
      Bv[e] = B0[e]; Bv[4 + e] = B1[e]; Bv[8 + e] = B2[e]; Bv[12 + e] = B3[e];
    }
    #pragma unroll
    for (int s = 0; s < NDS; ++s) {
      float dA = __expf(d * Av[s]);
      h[s] = dA * h[s] + du * Bv[s];
    }
    float sum01 = 0.f, sum23 = 0.f;
    #pragma unroll
    for (int s = 0; s < 8; ++s)  sum01 += h[s];
    #pragma unroll
    for (int s = 8; s < 16; ++s) sum23 += h[s];
    float y = sum01 + sum23 + u * dcoef;
    float z = bf2f(zp[(size_t)j * (2 * NDI)]);
    y *= z / (1.f + __expf(-z));
    ylds[j & 15][tid] = y;

    if ((j & 15) == 15) {
      __syncthreads();
      const int jb = j - 15;
      #pragma unroll
      for (int s2 = 0; s2 < 2; ++s2) {
        int u2 = tid + 256 * s2;
        int tt = u2 & 15, q = u2 >> 4;
        short8 v;
        #pragma unroll
        for (int e = 0; e < 8; ++e) v[e] = f2bf(ylds[tt][q * 8 + e]);
        int grow = b * NL + t0 + jb + tt;
        int k8 = (cb0 >> 3) + q;
        *(short8*)&ybf[fgoff(grow, k8, NDI)] = v;
      }
      __syncthreads();
    }
  }
}

// ---------------------------------------------------------------------------
extern "C" void kernel_launch(void* const* d_in, const int* in_sizes, int n_in,
                              void* d_out, int out_size, void* d_ws, size_t ws_size,
                              hipStream_t stream) {
  const float* x      = (const float*)d_in[0];
  const float* W_in   = (const float*)d_in[1];
  const float* b_in   = (const float*)d_in[2];
  const float* conv_w = (const float*)d_in[3];
  const float* conv_b = (const float*)d_in[4];
  const float* W_x    = (const float*)d_in[5];
  const float* b_x    = (const float*)d_in[6];
  const float* W_dt   = (const float*)d_in[7];
  const float* b_dt   = (const float*)d_in[8];
  const float* A_log  = (const float*)d_in[9];
  const float* Dv     = (const float*)d_in[10];
  const float* W_out  = (const float*)d_in[11];
  const float* b_out  = (const float*)d_in[12];
  float* out = (float*)d_out;

  char* w = (char*)d_ws;
  short* xbf   = (short*)(w);                  // FG 4096x1024 bf16   8.39MB
  short* WtIn  = (short*)(w + 8388608);        // FG 4096x1024 bf16   8.39MB
  short* WtCat = (short*)(w + 16777216);       // FG 2176x2048 bf16   8.91MB
  short* WtOut = (short*)(w + 25690112);       // FG 1024x2048 bf16   4.19MB
  short* xzbf  = (short*)(w + 29884416);       // 4096x4096 bf16     33.55MB
  float* xhf   = (float*)(w + 63438848);       // 4096x2048 f32      33.55MB
  short* xhbf  = (short*)(w + 96993280);       // FG 4096x2048 bf16  16.78MB
  float* delta = (float*)(w + 113770496);      // 4096x2048 f32      33.55MB
  float* Bm    = (float*)(w + 147324928);      // 4096x16   f32       0.26MB
  short* ybf   = (short*)(w + 147587072);      // FG 4096x2048 bf16  16.78MB
  // scan scratch aliases buffers dead by scan time (8.39MB each):
  float* Pbuf  = (float*)(w);                  // aliases xbf
  float* Hend  = (float*)(w + 8388608);        // aliases WtIn
  float* Hin   = (float*)(w + 16777216);       // aliases WtCat head

  // 0) zero Wcat pad groups 129..135 (rows 2064..2175) once per call
  hipMemsetAsync((char*)WtCat + (size_t)129 * 65536, 0, 7 * 65536, stream);

  // 1) converts / weight transposes into FG layout
  cvt_fg_kernel<<<MROWS / 16, 256, 0, stream>>>(x, xbf);
  transpose_fg_kernel<<<dim3((2 * NDI) / 32, NDM / 64), dim3(32, 8), 0, stream>>>(
      W_in, WtIn, NDM, 2 * NDI);
  transpose_fg_kernel<<<dim3(NDI / 32, NDI / 64), dim3(32, 8), 0, stream>>>(
      W_dt, WtCat, NDI, NDI);
  wx_fg_kernel<<<16, 256, 0, stream>>>(W_x, WtCat);
  transpose_fg_kernel<<<dim3(NDM / 32, NDI / 64), dim3(32, 8), 0, stream>>>(
      W_out, WtOut, NDI, NDM);

  // 2) xz = x @ W_in + b_in -> bf16 row-major (EPI=2; 32x16 = 512 blocks)
  gemm_fg_kernel<128, 2><<<dim3((2 * NDI) / 128, MROWS / 256), 512, 0, stream>>>(
      xbf, WtIn, b_in, nullptr, xzbf, nullptr, nullptr,
      MROWS, 2 * NDI, NDM);

  // 3) depthwise conv + silu (reads bf16 xz; writes xhf f32 + xhbf FG)
  conv_silu_kernel<<<dim3(NDI / 512, MROWS / 16), 256, 0, stream>>>(
      xzbf, conv_w, conv_b, xhf, xhbf);

  // 4+5) fused: [delta | Bmat] = xh @ [W_dt | W_x[:,16:32]] (17x16 = 272)
  gemm_fg_kernel<128, 1><<<dim3(2176 / 128, MROWS / 256), 512, 0, stream>>>(
      xhbf, WtCat, b_dt, delta, nullptr, Bm, b_x,
      MROWS, NDI, NDI);

  // 6) selective scan (chunked: local scan -> chunk combine -> rescan+merge)
  scan_p1_kernel<<<(NB * NDI * CCH) / 256, 256, 0, stream>>>(
      delta, Bm, xhf, A_log, Pbuf, Hend);
  scan_p2_kernel<<<(NB * NDI * NDS) / 256, 256, 0, stream>>>(Pbuf, Hend, Hin);
  scan_p3_kernel<<<(NB * NDI * CCH) / 256, 256, 0, stream>>>(
      delta, Bm, xhf, A_log, Hin, Dv, xzbf, ybf);

  // 7) out = y @ W_out + b_out  (EPI=0, BN=64; 16x16 = 256 blocks)
  gemm_fg_kernel<64, 0><<<dim3(NDM / 64, MROWS / 256), 512, 0, stream>>>(
      ybf, WtOut, b_out, out, nullptr, nullptr, nullptr,
      MROWS, NDM, NDI);
}